// Round 9
// baseline (469.721 us; speedup 1.0000x reference)
//
#include <hip/hip_runtime.h>
#include <stdint.h>
#include <math.h>

#define NAG 8192
#define NB  144          // partial row stride: 128 feats + deg col(128) + pad to 9*16
#define BM  64           // M rows per block
#define BK  32           // K per tile (double-buffered)
#define NSPLIT 8         // K splits (fp16 private partials, no atomics)

typedef __attribute__((ext_vector_type(8))) short short8;
typedef __attribute__((ext_vector_type(4))) float floatx4;

__device__ __forceinline__ float bf2f(unsigned short u) {
    union { uint32_t i; float f; } v; v.i = ((uint32_t)u) << 16; return v.f;
}
__device__ __forceinline__ unsigned short f2bf(float f) {
    union { float f; uint32_t i; } v; v.f = f;
    uint32_t x = v.i;
    return (unsigned short)((x + 0x7FFFu + ((x >> 16) & 1u)) >> 16);  // RNE
}
__device__ __forceinline__ unsigned short f2h(float f) {
    union { _Float16 h; unsigned short u; } v; v.h = (_Float16)f; return v.u;
}
__device__ __forceinline__ float h2f(unsigned short u) {
    union { _Float16 h; unsigned short u; } v; v.u = u; return (float)v.h;
}
// async global->LDS DMA, 16 B/lane; lds dest wave-uniform base (+lane*16 implicit)
__device__ __forceinline__ void gload_lds16(const void* g, void* lds) {
    __builtin_amdgcn_global_load_lds(
        (const __attribute__((address_space(1))) uint32_t*)g,
        (__attribute__((address_space(3))) uint32_t*)lds, 16, 0, 0);
}

// ---------------- Kernel 0: detect float storage dtype from W1 raw bits ----------------
__global__ __launch_bounds__(64) void k0_init(
    int* __restrict__ flag, const unsigned short* __restrict__ W1raw)
{
    int big = 0;
    #pragma unroll
    for (int j = 0; j < 8; ++j) {
        float v = bf2f(W1raw[threadIdx.x * 8 + j]);
        if (!(fabsf(v) <= 1e6f)) big = 1;   // catches huge and NaN (fp32 mantissa noise)
    }
    unsigned long long m = __ballot(big);
    if (threadIdx.x == 0) *flag = (m != 0ull) ? 1 : 0;
}

// ---------------- Kernel 1: h = tanh(obs@W1+b1); write h_f32 and hT_bf16 ----------------
__global__ __launch_bounds__(256) void k1_encode(
    const void* __restrict__ obs,   // [8192][64] fp32 or bf16
    const void* __restrict__ W1,    // [64][128]
    const void* __restrict__ b1,    // [128]
    const int* __restrict__ flag,
    float* __restrict__ h_f32,      // [8192][128]
    unsigned short* __restrict__ hT)// [144][8192] bf16 (row128=ones, 129..143=0)
{
    __shared__ float obs_lds[32][68];
    __shared__ unsigned short ht_lds[128][33];
    const int t = threadIdx.x;
    const int abase = blockIdx.x * 32;
    const bool isf = (*flag != 0);

    {   // stage obs tile 32x64
        int a = t >> 3, c0 = (t & 7) * 8;
        if (isf) {
            const float* p = (const float*)obs;
            #pragma unroll
            for (int j = 0; j < 8; ++j)
                obs_lds[a][c0 + j] = p[(size_t)(abase + a) * 64 + c0 + j];
        } else {
            const unsigned short* p = (const unsigned short*)obs;
            #pragma unroll
            for (int j = 0; j < 8; ++j)
                obs_lds[a][c0 + j] = bf2f(p[(size_t)(abase + a) * 64 + c0 + j]);
        }
    }
    __syncthreads();

    const int o = t & 127;
    const int half = t >> 7;          // wave-uniform
    float acc[16];
    if (isf) {
        const float* Wp = (const float*)W1;
        float bias = ((const float*)b1)[o];
        #pragma unroll
        for (int i = 0; i < 16; ++i) acc[i] = bias;
        for (int k0 = 0; k0 < 64; k0 += 8) {
            float w[8];
            #pragma unroll
            for (int j = 0; j < 8; ++j) w[j] = Wp[(k0 + j) * 128 + o];
            #pragma unroll
            for (int j = 0; j < 8; ++j)
                #pragma unroll
                for (int i = 0; i < 16; ++i)
                    acc[i] = fmaf(obs_lds[half * 16 + i][k0 + j], w[j], acc[i]);
        }
    } else {
        const unsigned short* Wp = (const unsigned short*)W1;
        float bias = bf2f(((const unsigned short*)b1)[o]);
        #pragma unroll
        for (int i = 0; i < 16; ++i) acc[i] = bias;
        for (int k0 = 0; k0 < 64; k0 += 8) {
            float w[8];
            #pragma unroll
            for (int j = 0; j < 8; ++j) w[j] = bf2f(Wp[(k0 + j) * 128 + o]);
            #pragma unroll
            for (int j = 0; j < 8; ++j)
                #pragma unroll
                for (int i = 0; i < 16; ++i)
                    acc[i] = fmaf(obs_lds[half * 16 + i][k0 + j], w[j], acc[i]);
        }
    }
    #pragma unroll
    for (int i = 0; i < 16; ++i) {
        float th = tanhf(acc[i]);
        int a = half * 16 + i;
        h_f32[(size_t)(abase + a) * 128 + o] = th;
        ht_lds[o][a] = f2bf(th);
    }
    __syncthreads();

    for (int p = 0; p < 18; ++p) {
        int n = p * 8 + (t >> 5);
        int a = t & 31;
        unsigned short v;
        if (n < 128)       v = ht_lds[n][a];
        else if (n == 128) v = 0x3F80;     // 1.0 bf16 -> deg column
        else               v = 0;
        hT[(size_t)n * NAG + abase + a] = v;
    }
}

// ---------------- Kernel 2: Cp16[ks] = adj[:, kslice] @ [h|1|0]  (bf16 MFMA) ----------------
// DMA-only staging + LDS DOUBLE BUFFER (BK=32): issue tile t+1's global_load_lds into the
// other buffer right after the barrier, compute tile t; the compiler's vmcnt(0)-before-
// s_barrier drains exactly at the next tile's pre-compute barrier -> one full tile of
// DMA/compute overlap with ZERO registers live across compute (spill-proof by design).
// XOR source-swizzle at DMA issue -> conflict-light fragment reads (A: ch^(row&7),
// B: ch^((row>>1)&3)). A staged raw int32; {0,1}->bf16 at fragment read via (x|y<<16)*0x3F80.
__global__ __launch_bounds__(256, 4) void k2_msggemm(
    const int* __restrict__ adj,              // [8192][8192] int32 {0,1}
    const unsigned short* __restrict__ hT,    // [144][8192] bf16
    unsigned short* __restrict__ Cp16)        // [NSPLIT][8192][144] fp16
{
    __shared__ __align__(16) int Alds0[64 * BK];              // 8192 B
    __shared__ __align__(16) int Alds1[64 * BK];              // 8192 B
    __shared__ __align__(16) unsigned short Blds0[144 * BK];  // 9216 B
    __shared__ __align__(16) unsigned short Blds1[144 * BK];  // 9216 B  (total 34816 B)
    const int t = threadIdx.x;
    const int mtile = blockIdx.x & 127;       // 128 M-tiles of 64 rows
    const int ks = blockIdx.x >> 7;           // 8 K-splits of 1024
    const int row0 = mtile * BM;
    const int kbeg = ks * 1024;

    const int wave = t >> 6, lane = t & 63;
    const int fm = lane & 15, quad = lane >> 4;

    floatx4 acc[9];
    #pragma unroll
    for (int i = 0; i < 9; ++i) acc[i] = (floatx4)0.f;

    // --- DMA source pointers (lane-permuted for swizzle) ---
    // A call s covers rows s*32 + wave*8 + (lane>>3); phys chunk p=lane&7; src chunk c=p^(row&7)
    const int rowA = wave * 8 + (lane >> 3);                  // s=0 row; s=1 adds 32 (row&7 same)
    const int cA = (lane & 7) ^ (rowA & 7);
    const int* aS0 = adj + (size_t)(row0 + rowA) * NAG + kbeg + cA * 4;
    const int* aS1 = adj + (size_t)(row0 + rowA + 32) * NAG + kbeg + cA * 4;
    // B call s covers rows s*64 + wave*16 + (lane>>2); p=lane&3; c=p^((row>>1)&3)
    const int rowB = wave * 16 + (lane >> 2);                 // s=1 adds 64 ((row>>1)&3 same)
    const int cB = (lane & 3) ^ ((rowB >> 1) & 3);
    const unsigned short* bS0 = hT + (size_t)rowB * NAG + kbeg + cB * 8;
    const unsigned short* bS1 = hT + (size_t)(rowB + 64) * NAG + kbeg + cB * 8;
    // wave-uniform LDS dest bases
    int* Ad00 = Alds0 + wave * 256;  int* Ad01 = Alds0 + 1024 + wave * 256;
    int* Ad10 = Alds1 + wave * 256;  int* Ad11 = Alds1 + 1024 + wave * 256;
    unsigned short* Bd00 = Blds0 + wave * 512;  unsigned short* Bd01 = Blds0 + 2048 + wave * 512;
    unsigned short* Bd10 = Blds1 + wave * 512;  unsigned short* Bd11 = Blds1 + 2048 + wave * 512;

    // constant B rows 128..143 (uniform within row -> swizzle-invariant), both buffers, once
    {
        int rr = 128 + (t >> 4);
        int off = (t & 15) * 2;
        uint32_t vv = (rr == 128) ? 0x3F803F80u : 0u;   // bf16 1.0|1.0 deg row
        *reinterpret_cast<uint32_t*>(&Blds0[rr * BK + off]) = vv;
        *reinterpret_cast<uint32_t*>(&Blds1[rr * BK + off]) = vv;
    }

#define DMA(T, Ad0_, Ad1_, Bd0_, Bd1_) do { \
        gload_lds16(aS0 + (T) * BK, (Ad0_)); \
        gload_lds16(aS1 + (T) * BK, (Ad1_)); \
        gload_lds16(bS0 + (T) * BK, (Bd0_)); \
        gload_lds16(bS1 + (T) * BK, (Bd1_)); \
    } while (0)
#define COMPUTE(Ab, Bb) do { \
        const int arow = (wave * 16 + fm) * BK; \
        int4 v0 = *reinterpret_cast<const int4*>(&(Ab)[arow + (((quad * 2 + 0) ^ (fm & 7)) << 2)]); \
        int4 v1 = *reinterpret_cast<const int4*>(&(Ab)[arow + (((quad * 2 + 1) ^ (fm & 7)) << 2)]); \
        union { uint32_t u[4]; short8 s; } af; \
        af.u[0] = ((uint32_t)v0.x | ((uint32_t)v0.y << 16)) * 0x3F80u; \
        af.u[1] = ((uint32_t)v0.z | ((uint32_t)v0.w << 16)) * 0x3F80u; \
        af.u[2] = ((uint32_t)v1.x | ((uint32_t)v1.y << 16)) * 0x3F80u; \
        af.u[3] = ((uint32_t)v1.z | ((uint32_t)v1.w << 16)) * 0x3F80u; \
        const int bphys = (quad ^ ((fm >> 1) & 3)) << 3; \
        _Pragma("unroll") \
        for (int j = 0; j < 9; ++j) { \
            short8 bf = *reinterpret_cast<const short8*>(&(Bb)[(j * 16 + fm) * BK + bphys]); \
            acc[j] = __builtin_amdgcn_mfma_f32_16x16x32_bf16(af.s, bf, acc[j], 0, 0, 0); \
        } \
    } while (0)

    DMA(0, Ad00, Ad01, Bd00, Bd01);   // preamble: tile 0 -> buf0

    for (int it = 0; it < 32; it += 2) {
        __syncthreads();                              // drains DMA(it) -> buf0 ready
        DMA(it + 1, Ad10, Ad11, Bd10, Bd11);          // tile it+1 -> buf1, in flight during compute
        COMPUTE(Alds0, Blds0);                        // tile it
        __syncthreads();                              // drains DMA(it+1) -> buf1 ready
        if (it + 2 < 32) DMA(it + 2, Ad00, Ad01, Bd00, Bd01);
        COMPUTE(Alds1, Blds1);                        // tile it+1
    }

    // epilogue: C/D layout col=lane&15, row=quad*4+reg; fp16 private partial per K-split
    unsigned short* out = Cp16 + (size_t)ks * (NAG * NB);
    #pragma unroll
    for (int j = 0; j < 9; ++j) {
        int col = j * 16 + fm;
        #pragma unroll
        for (int r = 0; r < 4; ++r) {
            int row = row0 + wave * 16 + quad * 4 + r;
            out[(size_t)row * NB + col] = f2h(acc[j][r]);
        }
    }
#undef DMA
#undef COMPUTE
}

// ---------------- Kernel 3: reduce fp16 partials, msg=sum/deg, actor MLP ----------------
__global__ __launch_bounds__(256) void k3_actor(
    const float* __restrict__ h_f32,          // [8192][128]
    const unsigned short* __restrict__ Cp16,  // [NSPLIT][8192][144] fp16
    const void* __restrict__ W2,              // [256][128]
    const void* __restrict__ b2,              // [128]
    const void* __restrict__ W3,              // [128][16]
    const void* __restrict__ b3,              // [16]
    const int* __restrict__ flag,
    void* __restrict__ out)                   // [8192][16]
{
    __shared__ float4 comb4[16][66];   // [agent][c-quad], c = 0..255
    __shared__ float hid[16][132];
    __shared__ float inv_lds[16];
    const int t = threadIdx.x;
    const int abase = blockIdx.x * 16;
    const bool isf = (*flag != 0);
    const size_t PS = (size_t)NAG * NB;

    if (t < 16) {
        float deg = 0.f;
        #pragma unroll
        for (int s = 0; s < NSPLIT; ++s)
            deg += h2f(Cp16[s * PS + (size_t)(abase + t) * NB + 128]);
        inv_lds[t] = 1.0f / fmaxf(deg, 1.0f);
    }
    __syncthreads();

    #pragma unroll
    for (int jj = 0; jj < 4; ++jj) {
        int idx = jj * 256 + t;
        int a = idx >> 6, q = idx & 63;
        float4 v;
        if (q < 32) {   // h part
            v = *reinterpret_cast<const float4*>(h_f32 + (size_t)(abase + a) * 128 + q * 4);
        } else {        // msg part: sum NSPLIT fp16 partials, scale by 1/deg
            int f = (q - 32) * 4;
            float s0 = 0.f, s1 = 0.f, s2 = 0.f, s3 = 0.f;
            #pragma unroll
            for (int s = 0; s < NSPLIT; ++s) {
                ushort4 p = *reinterpret_cast<const ushort4*>(Cp16 + s * PS + (size_t)(abase + a) * NB + f);
                s0 += h2f(p.x); s1 += h2f(p.y); s2 += h2f(p.z); s3 += h2f(p.w);
            }
            float sc = inv_lds[a];
            v = make_float4(s0 * sc, s1 * sc, s2 * sc, s3 * sc);
        }
        comb4[a][q] = v;
    }
    __syncthreads();

    const int o = t & 127, half = t >> 7;   // 8 agents per half
    float acc[8];
    if (isf) {
        const float* Wp = (const float*)W2;
        float bias = ((const float*)b2)[o];
        #pragma unroll
        for (int i = 0; i < 8; ++i) acc[i] = bias;
        for (int cq = 0; cq < 64; ++cq) {
            float w0 = Wp[(cq * 4 + 0) * 128 + o];
            float w1 = Wp[(cq * 4 + 1) * 128 + o];
            float w2 = Wp[(cq * 4 + 2) * 128 + o];
            float w3 = Wp[(cq * 4 + 3) * 128 + o];
            #pragma unroll
            for (int i = 0; i < 8; ++i) {
                float4 v = comb4[half * 8 + i][cq];
                acc[i] = fmaf(v.x, w0, acc[i]);
                acc[i] = fmaf(v.y, w1, acc[i]);
                acc[i] = fmaf(v.z, w2, acc[i]);
                acc[i] = fmaf(v.w, w3, acc[i]);
            }
        }
    } else {
        const unsigned short* Wp = (const unsigned short*)W2;
        float bias = bf2f(((const unsigned short*)b2)[o]);
        #pragma unroll
        for (int i = 0; i < 8; ++i) acc[i] = bias;
        for (int cq = 0; cq < 64; ++cq) {
            float w0 = bf2f(Wp[(cq * 4 + 0) * 128 + o]);
            float w1 = bf2f(Wp[(cq * 4 + 1) * 128 + o]);
            float w2 = bf2f(Wp[(cq * 4 + 2) * 128 + o]);
            float w3 = bf2f(Wp[(cq * 4 + 3) * 128 + o]);
            #pragma unroll
            for (int i = 0; i < 8; ++i) {
                float4 v = comb4[half * 8 + i][cq];
                acc[i] = fmaf(v.x, w0, acc[i]);
                acc[i] = fmaf(v.y, w1, acc[i]);
                acc[i] = fmaf(v.z, w2, acc[i]);
                acc[i] = fmaf(v.w, w3, acc[i]);
            }
        }
    }
    #pragma unroll
    for (int i = 0; i < 8; ++i)
        hid[half * 8 + i][o] = tanhf(acc[i]);
    __syncthreads();

    const int q = t & 15, ar = t >> 4;
    float l;
    if (isf) {
        const float* Wp = (const float*)W3;
        l = ((const float*)b3)[q];
        #pragma unroll 4
        for (int oo = 0; oo < 128; ++oo)
            l = fmaf(hid[ar][oo], Wp[oo * 16 + q], l);
    } else {
        const unsigned short* Wp = (const unsigned short*)W3;
        l = bf2f(((const unsigned short*)b3)[q]);
        #pragma unroll 4
        for (int oo = 0; oo < 128; ++oo)
            l = fmaf(hid[ar][oo], bf2f(Wp[oo * 16 + q]), l);
    }
    size_t i0 = (size_t)(abase + ar) * 16 + q;
    if (isf) ((float*)out)[i0] = l;
    else     ((unsigned short*)out)[i0] = f2bf(l);
}

extern "C" void kernel_launch(void* const* d_in, const int* in_sizes, int n_in,
                              void* d_out, int out_size, void* d_ws, size_t ws_size,
                              hipStream_t stream) {
    const void* obs = d_in[0];
    const int*  adj = (const int*)d_in[1];
    const void* W1  = d_in[2];
    const void* b1  = d_in[3];
    const void* W2  = d_in[4];
    const void* b2  = d_in[5];
    const void* W3  = d_in[6];
    const void* b3  = d_in[7];

    char* ws = (char*)d_ws;
    unsigned short* hT   = (unsigned short*)(ws);               // 144*8192*2   =  2,359,296 B
    float*          h_f32= (float*)(ws + 2359296);              // 8192*128*4   =  4,194,304 B
    unsigned short* Cp16 = (unsigned short*)(ws + 6553600);     // 8*8192*144*2 = 18,874,368 B
    int*            flag = (int*)(ws + 25427968);               // 4 B  (total ~25.4 MB)

    hipLaunchKernelGGL(k0_init, dim3(1), dim3(64), 0, stream, flag, (const unsigned short*)W1);
    hipLaunchKernelGGL(k1_encode, dim3(256), dim3(256), 0, stream, obs, W1, b1, flag, h_f32, hT);
    hipLaunchKernelGGL(k2_msggemm, dim3(1024), dim3(256), 0, stream, adj, hT, Cp16);
    hipLaunchKernelGGL(k3_actor, dim3(512), dim3(256), 0, stream, h_f32, Cp16, W2, b2, W3, b3, flag, d_out);
}

// Round 10
// 460.322 us; speedup vs baseline: 1.0204x; 1.0204x over previous
//
#include <hip/hip_runtime.h>
#include <stdint.h>
#include <math.h>

#define NAG 8192
#define NB  144          // partial row stride: 128 feats + deg col(128) + pad to 9*16
#define BM  64           // M rows per block
#define BK  32           // K per tile (B double-buffered)
#define NSPLIT 16        // K splits (fp16 private partials, no atomics)

typedef __attribute__((ext_vector_type(8))) short short8;
typedef __attribute__((ext_vector_type(4))) float floatx4;

__device__ __forceinline__ float bf2f(unsigned short u) {
    union { uint32_t i; float f; } v; v.i = ((uint32_t)u) << 16; return v.f;
}
__device__ __forceinline__ unsigned short f2bf(float f) {
    union { float f; uint32_t i; } v; v.f = f;
    uint32_t x = v.i;
    return (unsigned short)((x + 0x7FFFu + ((x >> 16) & 1u)) >> 16);  // RNE
}
__device__ __forceinline__ unsigned short f2h(float f) {
    union { _Float16 h; unsigned short u; } v; v.h = (_Float16)f; return v.u;
}
__device__ __forceinline__ float h2f(unsigned short u) {
    union { _Float16 h; unsigned short u; } v; v.u = u; return (float)v.h;
}
// async global->LDS DMA, 16 B/lane; lds dest wave-uniform base (+lane*16 implicit)
__device__ __forceinline__ void gload_lds16(const void* g, void* lds) {
    __builtin_amdgcn_global_load_lds(
        (const __attribute__((address_space(1))) uint32_t*)g,
        (__attribute__((address_space(3))) uint32_t*)lds, 16, 0, 0);
}

// ---------------- Kernel 0: detect float storage dtype from W1 raw bits ----------------
__global__ __launch_bounds__(64) void k0_init(
    int* __restrict__ flag, const unsigned short* __restrict__ W1raw)
{
    int big = 0;
    #pragma unroll
    for (int j = 0; j < 8; ++j) {
        float v = bf2f(W1raw[threadIdx.x * 8 + j]);
        if (!(fabsf(v) <= 1e6f)) big = 1;   // catches huge and NaN (fp32 mantissa noise)
    }
    unsigned long long m = __ballot(big);
    if (threadIdx.x == 0) *flag = (m != 0ull) ? 1 : 0;
}

// ---------------- Kernel 1: h = tanh(obs@W1+b1); write h_f32 and hT_bf16 ----------------
__global__ __launch_bounds__(256) void k1_encode(
    const void* __restrict__ obs,   // [8192][64] fp32 or bf16
    const void* __restrict__ W1,    // [64][128]
    const void* __restrict__ b1,    // [128]
    const int* __restrict__ flag,
    float* __restrict__ h_f32,      // [8192][128]
    unsigned short* __restrict__ hT)// [144][8192] bf16 (row128=ones, 129..143=0)
{
    __shared__ float obs_lds[32][68];
    __shared__ unsigned short ht_lds[128][33];
    const int t = threadIdx.x;
    const int abase = blockIdx.x * 32;
    const bool isf = (*flag != 0);

    {   // stage obs tile 32x64
        int a = t >> 3, c0 = (t & 7) * 8;
        if (isf) {
            const float* p = (const float*)obs;
            #pragma unroll
            for (int j = 0; j < 8; ++j)
                obs_lds[a][c0 + j] = p[(size_t)(abase + a) * 64 + c0 + j];
        } else {
            const unsigned short* p = (const unsigned short*)obs;
            #pragma unroll
            for (int j = 0; j < 8; ++j)
                obs_lds[a][c0 + j] = bf2f(p[(size_t)(abase + a) * 64 + c0 + j]);
        }
    }
    __syncthreads();

    const int o = t & 127;
    const int half = t >> 7;          // wave-uniform
    float acc[16];
    if (isf) {
        const float* Wp = (const float*)W1;
        float bias = ((const float*)b1)[o];
        #pragma unroll
        for (int i = 0; i < 16; ++i) acc[i] = bias;
        for (int k0 = 0; k0 < 64; k0 += 8) {
            float w[8];
            #pragma unroll
            for (int j = 0; j < 8; ++j) w[j] = Wp[(k0 + j) * 128 + o];
            #pragma unroll
            for (int j = 0; j < 8; ++j)
                #pragma unroll
                for (int i = 0; i < 16; ++i)
                    acc[i] = fmaf(obs_lds[half * 16 + i][k0 + j], w[j], acc[i]);
        }
    } else {
        const unsigned short* Wp = (const unsigned short*)W1;
        float bias = bf2f(((const unsigned short*)b1)[o]);
        #pragma unroll
        for (int i = 0; i < 16; ++i) acc[i] = bias;
        for (int k0 = 0; k0 < 64; k0 += 8) {
            float w[8];
            #pragma unroll
            for (int j = 0; j < 8; ++j) w[j] = bf2f(Wp[(k0 + j) * 128 + o]);
            #pragma unroll
            for (int j = 0; j < 8; ++j)
                #pragma unroll
                for (int i = 0; i < 16; ++i)
                    acc[i] = fmaf(obs_lds[half * 16 + i][k0 + j], w[j], acc[i]);
        }
    }
    #pragma unroll
    for (int i = 0; i < 16; ++i) {
        float th = tanhf(acc[i]);
        int a = half * 16 + i;
        h_f32[(size_t)(abase + a) * 128 + o] = th;
        ht_lds[o][a] = f2bf(th);
    }
    __syncthreads();

    for (int p = 0; p < 18; ++p) {
        int n = p * 8 + (t >> 5);
        int a = t & 31;
        unsigned short v;
        if (n < 128)       v = ht_lds[n][a];
        else if (n == 128) v = 0x3F80;     // 1.0 bf16 -> deg column
        else               v = 0;
        hT[(size_t)n * NAG + abase + a] = v;
    }
}

// ---------------- Kernel 2: Cp16[ks] = adj[:, kslice] @ [h|1|0]  (bf16 MFMA) ----------------
// A has ZERO cross-wave reuse -> bypass LDS: each lane reads its MFMA A-fragment straight
// from global (2x dwordx4, coalesced 128B/row segments), packs {0,1}->bf16 in regs, feeds
// MFMA immediately (nothing register-resident across barriers -> spill-proof). Only B
// (shared by all waves, L2-hot: hT=2.4MB) goes through the DMA double buffer; its ~250cyc
// L2 latency hides fully under compute. A's HBM latency is hidden by wave TLP (NSPLIT=16
// -> 2048 blocks, ~6 blocks/CU at LDS 18.4KB).
__global__ __launch_bounds__(256, 4) void k2_msggemm(
    const int* __restrict__ adj,              // [8192][8192] int32 {0,1}
    const unsigned short* __restrict__ hT,    // [144][8192] bf16
    unsigned short* __restrict__ Cp16)        // [NSPLIT][8192][144] fp16
{
    __shared__ __align__(16) unsigned short Blds0[144 * BK];  // 9216 B
    __shared__ __align__(16) unsigned short Blds1[144 * BK];  // 9216 B
    const int t = threadIdx.x;
    const int mtile = blockIdx.x & 127;       // 128 M-tiles of 64 rows
    const int ks = blockIdx.x >> 7;           // 16 K-splits of 512
    const int row0 = mtile * BM;
    const int kbeg = ks * 512;

    const int wave = t >> 6, lane = t & 63;
    const int fm = lane & 15, quad = lane >> 4;

    floatx4 acc[9];
    #pragma unroll
    for (int i = 0; i < 9; ++i) acc[i] = (floatx4)0.f;

    // A direct-from-global: lane reads row (row0+wave*16+fm), ints kbeg+it*BK+quad*8..+7
    const int* aP = adj + (size_t)(row0 + wave * 16 + fm) * NAG + kbeg + quad * 8;

    // B DMA source (lane-permuted XOR swizzle, as round 9): call s covers rows s*64 + wave*16 + (lane>>2)
    const int rowB = wave * 16 + (lane >> 2);
    const int cB = (lane & 3) ^ ((rowB >> 1) & 3);
    const unsigned short* bS0 = hT + (size_t)rowB * NAG + kbeg + cB * 8;
    const unsigned short* bS1 = hT + (size_t)(rowB + 64) * NAG + kbeg + cB * 8;
    unsigned short* Bd00 = Blds0 + wave * 512;  unsigned short* Bd01 = Blds0 + 2048 + wave * 512;
    unsigned short* Bd10 = Blds1 + wave * 512;  unsigned short* Bd11 = Blds1 + 2048 + wave * 512;

    // constant B rows 128..143 (uniform within row -> swizzle-invariant), both buffers, once
    {
        int rr = 128 + (t >> 4);
        int off = (t & 15) * 2;
        uint32_t vv = (rr == 128) ? 0x3F803F80u : 0u;   // bf16 1.0|1.0 deg row
        *reinterpret_cast<uint32_t*>(&Blds0[rr * BK + off]) = vv;
        *reinterpret_cast<uint32_t*>(&Blds1[rr * BK + off]) = vv;
    }

#define DMAB(T, Bd0_, Bd1_) do { \
        gload_lds16(bS0 + (T) * BK, (Bd0_)); \
        gload_lds16(bS1 + (T) * BK, (Bd1_)); \
    } while (0)
#define COMPUTE(T, Bb) do { \
        int4 v0 = *reinterpret_cast<const int4*>(aP + (T) * BK); \
        int4 v1 = *reinterpret_cast<const int4*>(aP + (T) * BK + 4); \
        union { uint32_t u[4]; short8 s; } af; \
        af.u[0] = ((uint32_t)v0.x | ((uint32_t)v0.y << 16)) * 0x3F80u; \
        af.u[1] = ((uint32_t)v0.z | ((uint32_t)v0.w << 16)) * 0x3F80u; \
        af.u[2] = ((uint32_t)v1.x | ((uint32_t)v1.y << 16)) * 0x3F80u; \
        af.u[3] = ((uint32_t)v1.z | ((uint32_t)v1.w << 16)) * 0x3F80u; \
        const int bphys = (quad ^ ((fm >> 1) & 3)) << 3; \
        _Pragma("unroll") \
        for (int j = 0; j < 9; ++j) { \
            short8 bf = *reinterpret_cast<const short8*>(&(Bb)[(j * 16 + fm) * BK + bphys]); \
            acc[j] = __builtin_amdgcn_mfma_f32_16x16x32_bf16(af.s, bf, acc[j], 0, 0, 0); \
        } \
    } while (0)

    DMAB(0, Bd00, Bd01);   // preamble: B tile 0 -> buf0

    for (int it = 0; it < 16; it += 2) {
        __syncthreads();                      // buf0 ready (drains B DMA)
        DMAB(it + 1, Bd10, Bd11);             // B tile it+1 -> buf1, in flight during compute
        COMPUTE(it, Blds0);
        __syncthreads();                      // buf1 ready
        if (it + 2 < 16) DMAB(it + 2, Bd00, Bd01);
        COMPUTE(it + 1, Blds1);
    }

    // epilogue: C/D layout col=lane&15, row=quad*4+reg; fp16 private partial per K-split
    unsigned short* out = Cp16 + (size_t)ks * (NAG * NB);
    #pragma unroll
    for (int j = 0; j < 9; ++j) {
        int col = j * 16 + fm;
        #pragma unroll
        for (int r = 0; r < 4; ++r) {
            int row = row0 + wave * 16 + quad * 4 + r;
            out[(size_t)row * NB + col] = f2h(acc[j][r]);
        }
    }
#undef DMAB
#undef COMPUTE
}

// ---------------- Kernel 3: reduce fp16 partials, msg=sum/deg, actor MLP ----------------
__global__ __launch_bounds__(256) void k3_actor(
    const float* __restrict__ h_f32,          // [8192][128]
    const unsigned short* __restrict__ Cp16,  // [NSPLIT][8192][144] fp16
    const void* __restrict__ W2,              // [256][128]
    const void* __restrict__ b2,              // [128]
    const void* __restrict__ W3,              // [128][16]
    const void* __restrict__ b3,              // [16]
    const int* __restrict__ flag,
    void* __restrict__ out)                   // [8192][16]
{
    __shared__ float4 comb4[16][66];   // [agent][c-quad], c = 0..255
    __shared__ float hid[16][132];
    __shared__ float inv_lds[16];
    const int t = threadIdx.x;
    const int abase = blockIdx.x * 16;
    const bool isf = (*flag != 0);
    const size_t PS = (size_t)NAG * NB;

    if (t < 16) {
        float deg = 0.f;
        #pragma unroll
        for (int s = 0; s < NSPLIT; ++s)
            deg += h2f(Cp16[s * PS + (size_t)(abase + t) * NB + 128]);
        inv_lds[t] = 1.0f / fmaxf(deg, 1.0f);
    }
    __syncthreads();

    #pragma unroll
    for (int jj = 0; jj < 4; ++jj) {
        int idx = jj * 256 + t;
        int a = idx >> 6, q = idx & 63;
        float4 v;
        if (q < 32) {   // h part
            v = *reinterpret_cast<const float4*>(h_f32 + (size_t)(abase + a) * 128 + q * 4);
        } else {        // msg part: sum NSPLIT fp16 partials, scale by 1/deg
            int f = (q - 32) * 4;
            float s0 = 0.f, s1 = 0.f, s2 = 0.f, s3 = 0.f;
            #pragma unroll
            for (int s = 0; s < NSPLIT; ++s) {
                ushort4 p = *reinterpret_cast<const ushort4*>(Cp16 + s * PS + (size_t)(abase + a) * NB + f);
                s0 += h2f(p.x); s1 += h2f(p.y); s2 += h2f(p.z); s3 += h2f(p.w);
            }
            float sc = inv_lds[a];
            v = make_float4(s0 * sc, s1 * sc, s2 * sc, s3 * sc);
        }
        comb4[a][q] = v;
    }
    __syncthreads();

    const int o = t & 127, half = t >> 7;   // 8 agents per half
    float acc[8];
    if (isf) {
        const float* Wp = (const float*)W2;
        float bias = ((const float*)b2)[o];
        #pragma unroll
        for (int i = 0; i < 8; ++i) acc[i] = bias;
        for (int cq = 0; cq < 64; ++cq) {
            float w0 = Wp[(cq * 4 + 0) * 128 + o];
            float w1 = Wp[(cq * 4 + 1) * 128 + o];
            float w2 = Wp[(cq * 4 + 2) * 128 + o];
            float w3 = Wp[(cq * 4 + 3) * 128 + o];
            #pragma unroll
            for (int i = 0; i < 8; ++i) {
                float4 v = comb4[half * 8 + i][cq];
                acc[i] = fmaf(v.x, w0, acc[i]);
                acc[i] = fmaf(v.y, w1, acc[i]);
                acc[i] = fmaf(v.z, w2, acc[i]);
                acc[i] = fmaf(v.w, w3, acc[i]);
            }
        }
    } else {
        const unsigned short* Wp = (const unsigned short*)W2;
        float bias = bf2f(((const unsigned short*)b2)[o]);
        #pragma unroll
        for (int i = 0; i < 8; ++i) acc[i] = bias;
        for (int cq = 0; cq < 64; ++cq) {
            float w0 = bf2f(Wp[(cq * 4 + 0) * 128 + o]);
            float w1 = bf2f(Wp[(cq * 4 + 1) * 128 + o]);
            float w2 = bf2f(Wp[(cq * 4 + 2) * 128 + o]);
            float w3 = bf2f(Wp[(cq * 4 + 3) * 128 + o]);
            #pragma unroll
            for (int i = 0; i < 8; ++i) {
                float4 v = comb4[half * 8 + i][cq];
                acc[i] = fmaf(v.x, w0, acc[i]);
                acc[i] = fmaf(v.y, w1, acc[i]);
                acc[i] = fmaf(v.z, w2, acc[i]);
                acc[i] = fmaf(v.w, w3, acc[i]);
            }
        }
    }
    #pragma unroll
    for (int i = 0; i < 8; ++i)
        hid[half * 8 + i][o] = tanhf(acc[i]);
    __syncthreads();

    const int q = t & 15, ar = t >> 4;
    float l;
    if (isf) {
        const float* Wp = (const float*)W3;
        l = ((const float*)b3)[q];
        #pragma unroll 4
        for (int oo = 0; oo < 128; ++oo)
            l = fmaf(hid[ar][oo], Wp[oo * 16 + q], l);
    } else {
        const unsigned short* Wp = (const unsigned short*)W3;
        l = bf2f(((const unsigned short*)b3)[q]);
        #pragma unroll 4
        for (int oo = 0; oo < 128; ++oo)
            l = fmaf(hid[ar][oo], bf2f(Wp[oo * 16 + q]), l);
    }
    size_t i0 = (size_t)(abase + ar) * 16 + q;
    if (isf) ((float*)out)[i0] = l;
    else     ((unsigned short*)out)[i0] = f2bf(l);
}

extern "C" void kernel_launch(void* const* d_in, const int* in_sizes, int n_in,
                              void* d_out, int out_size, void* d_ws, size_t ws_size,
                              hipStream_t stream) {
    const void* obs = d_in[0];
    const int*  adj = (const int*)d_in[1];
    const void* W1  = d_in[2];
    const void* b1  = d_in[3];
    const void* W2  = d_in[4];
    const void* b2  = d_in[5];
    const void* W3  = d_in[6];
    const void* b3  = d_in[7];

    char* ws = (char*)d_ws;
    unsigned short* hT   = (unsigned short*)(ws);               // 144*8192*2    =  2,359,296 B
    float*          h_f32= (float*)(ws + 2359296);              // 8192*128*4    =  4,194,304 B
    unsigned short* Cp16 = (unsigned short*)(ws + 6553600);     // 16*8192*144*2 = 37,748,736 B
    int*            flag = (int*)(ws + 44302336);               // 4 B  (total ~44.3 MB)

    hipLaunchKernelGGL(k0_init, dim3(1), dim3(64), 0, stream, flag, (const unsigned short*)W1);
    hipLaunchKernelGGL(k1_encode, dim3(256), dim3(256), 0, stream, obs, W1, b1, flag, h_f32, hT);
    hipLaunchKernelGGL(k2_msggemm, dim3(2048), dim3(256), 0, stream, adj, hT, Cp16);
    hipLaunchKernelGGL(k3_actor, dim3(512), dim3(256), 0, stream, h_f32, Cp16, W2, b2, W3, b3, flag, d_out);
}

// Round 11
// 457.755 us; speedup vs baseline: 1.0261x; 1.0056x over previous
//
#include <hip/hip_runtime.h>
#include <stdint.h>
#include <math.h>

#define NAG 8192
#define NB  144          // partial row stride: 128 feats + deg col(128) + pad to 9*16
#define BM  128          // M rows per block (8 waves x 16-row strip)
#define NSPLIT 32        // K splits of 256 (fp16 private partials, no atomics)
#define LDB 264          // B LDS row stride in shorts (256 + 8 pad; mult of 8 -> b128 aligned)

typedef __attribute__((ext_vector_type(8))) short short8;
typedef __attribute__((ext_vector_type(4))) float floatx4;

__device__ __forceinline__ float bf2f(unsigned short u) {
    union { uint32_t i; float f; } v; v.i = ((uint32_t)u) << 16; return v.f;
}
__device__ __forceinline__ unsigned short f2bf(float f) {
    union { float f; uint32_t i; } v; v.f = f;
    uint32_t x = v.i;
    return (unsigned short)((x + 0x7FFFu + ((x >> 16) & 1u)) >> 16);  // RNE
}
__device__ __forceinline__ unsigned short f2h(float f) {
    union { _Float16 h; unsigned short u; } v; v.h = (_Float16)f; return v.u;
}
__device__ __forceinline__ float h2f(unsigned short u) {
    union { _Float16 h; unsigned short u; } v; v.u = u; return (float)v.h;
}

// ---------------- Kernel 0: detect float storage dtype from W1 raw bits ----------------
__global__ __launch_bounds__(64) void k0_init(
    int* __restrict__ flag, const unsigned short* __restrict__ W1raw)
{
    int big = 0;
    #pragma unroll
    for (int j = 0; j < 8; ++j) {
        float v = bf2f(W1raw[threadIdx.x * 8 + j]);
        if (!(fabsf(v) <= 1e6f)) big = 1;   // catches huge and NaN (fp32 mantissa noise)
    }
    unsigned long long m = __ballot(big);
    if (threadIdx.x == 0) *flag = (m != 0ull) ? 1 : 0;
}

// ---------------- Kernel 1: h = tanh(obs@W1+b1); write h_f32 and hT_bf16 ----------------
__global__ __launch_bounds__(256) void k1_encode(
    const void* __restrict__ obs,   // [8192][64] fp32 or bf16
    const void* __restrict__ W1,    // [64][128]
    const void* __restrict__ b1,    // [128]
    const int* __restrict__ flag,
    float* __restrict__ h_f32,      // [8192][128]
    unsigned short* __restrict__ hT)// [144][8192] bf16 (row128=ones, 129..143=0)
{
    __shared__ float obs_lds[32][68];
    __shared__ unsigned short ht_lds[128][33];
    const int t = threadIdx.x;
    const int abase = blockIdx.x * 32;
    const bool isf = (*flag != 0);

    {   // stage obs tile 32x64
        int a = t >> 3, c0 = (t & 7) * 8;
        if (isf) {
            const float* p = (const float*)obs;
            #pragma unroll
            for (int j = 0; j < 8; ++j)
                obs_lds[a][c0 + j] = p[(size_t)(abase + a) * 64 + c0 + j];
        } else {
            const unsigned short* p = (const unsigned short*)obs;
            #pragma unroll
            for (int j = 0; j < 8; ++j)
                obs_lds[a][c0 + j] = bf2f(p[(size_t)(abase + a) * 64 + c0 + j]);
        }
    }
    __syncthreads();

    const int o = t & 127;
    const int half = t >> 7;          // wave-uniform
    float acc[16];
    if (isf) {
        const float* Wp = (const float*)W1;
        float bias = ((const float*)b1)[o];
        #pragma unroll
        for (int i = 0; i < 16; ++i) acc[i] = bias;
        for (int k0 = 0; k0 < 64; k0 += 8) {
            float w[8];
            #pragma unroll
            for (int j = 0; j < 8; ++j) w[j] = Wp[(k0 + j) * 128 + o];
            #pragma unroll
            for (int j = 0; j < 8; ++j)
                #pragma unroll
                for (int i = 0; i < 16; ++i)
                    acc[i] = fmaf(obs_lds[half * 16 + i][k0 + j], w[j], acc[i]);
        }
    } else {
        const unsigned short* Wp = (const unsigned short*)W1;
        float bias = bf2f(((const unsigned short*)b1)[o]);
        #pragma unroll
        for (int i = 0; i < 16; ++i) acc[i] = bias;
        for (int k0 = 0; k0 < 64; k0 += 8) {
            float w[8];
            #pragma unroll
            for (int j = 0; j < 8; ++j) w[j] = bf2f(Wp[(k0 + j) * 128 + o]);
            #pragma unroll
            for (int j = 0; j < 8; ++j)
                #pragma unroll
                for (int i = 0; i < 16; ++i)
                    acc[i] = fmaf(obs_lds[half * 16 + i][k0 + j], w[j], acc[i]);
        }
    }
    #pragma unroll
    for (int i = 0; i < 16; ++i) {
        float th = tanhf(acc[i]);
        int a = half * 16 + i;
        h_f32[(size_t)(abase + a) * 128 + o] = th;
        ht_lds[o][a] = f2bf(th);
    }
    __syncthreads();

    for (int p = 0; p < 18; ++p) {
        int n = p * 8 + (t >> 5);
        int a = t & 31;
        unsigned short v;
        if (n < 128)       v = ht_lds[n][a];
        else if (n == 128) v = 0x3F80;     // 1.0 bf16 -> deg column
        else               v = 0;
        hT[(size_t)n * NAG + abase + a] = v;
    }
}

// ---------------- Kernel 2: Cp16[ks] = adj[:, kslice] @ [h|1|0]  (bf16 MFMA) ----------------
// BARRIER-FREE K-loop (rounds 8-10 lesson: vmcnt is one counter, so the compiler's
// vmcnt(0)-before-s_barrier drains EVERY in-flight load at every barrier -- any
// global_load_lds + barrier structure serializes A's HBM latency with compute).
// Here: whole 144x256 B-slice loaded once into padded LDS (plain loads, ONE barrier),
// then 8 K-windows of pure {A direct-from-global -> pack -> 9 ds_read + 9 MFMA} with
// no syncs at all: wave TLP (16 waves/CU) hides A latency; LDS reads overlap HBM.
__global__ __launch_bounds__(512, 4) void k2_msggemm(
    const int* __restrict__ adj,              // [8192][8192] int32 {0,1}
    const unsigned short* __restrict__ hT,    // [144][8192] bf16
    unsigned short* __restrict__ Cp16)        // [NSPLIT][8192][144] fp16
{
    __shared__ __align__(16) unsigned short Blds[144 * LDB];  // 76,032 B -> 2 blocks/CU
    const int t = threadIdx.x;
    const int mtile = blockIdx.x & 63;        // 64 M-tiles of 128 rows
    const int ks = blockIdx.x >> 6;           // 32 K-splits of 256
    const int row0 = mtile * BM;
    const int kbeg = ks * 256;

    const int wave = t >> 6, lane = t & 63;
    const int fm = lane & 15, quad = lane >> 4;

    // ---- preamble: load B slice (144 rows x 256 k) into LDS, padded stride ----
    // 4608 16B-chunks over 512 threads = 9 each; consecutive t -> consecutive chunks (coalesced)
    #pragma unroll
    for (int i = 0; i < 9; ++i) {
        int idx = i * 512 + t;
        int row = idx >> 5, ch = idx & 31;
        uint4 v = *reinterpret_cast<const uint4*>(hT + (size_t)row * NAG + kbeg + ch * 8);
        *reinterpret_cast<uint4*>(&Blds[row * LDB + ch * 8]) = v;
    }
    __syncthreads();   // the ONLY barrier

    floatx4 acc[9];
    #pragma unroll
    for (int i = 0; i < 9; ++i) acc[i] = (floatx4)0.f;

    // A direct-from-global: lane reads row (row0 + wave*16 + fm), 8 ints at k + quad*8
    const int* aP = adj + (size_t)(row0 + wave * 16 + fm) * NAG + kbeg + quad * 8;

    for (int w = 0; w < 8; ++w) {             // 8 K-windows of 32
        int4 v0 = *reinterpret_cast<const int4*>(aP + w * 32);
        int4 v1 = *reinterpret_cast<const int4*>(aP + w * 32 + 4);
        union { uint32_t u[4]; short8 s; } af;
        af.u[0] = ((uint32_t)v0.x | ((uint32_t)v0.y << 16)) * 0x3F80u;
        af.u[1] = ((uint32_t)v0.z | ((uint32_t)v0.w << 16)) * 0x3F80u;
        af.u[2] = ((uint32_t)v1.x | ((uint32_t)v1.y << 16)) * 0x3F80u;
        af.u[3] = ((uint32_t)v1.z | ((uint32_t)v1.w << 16)) * 0x3F80u;
        #pragma unroll
        for (int j = 0; j < 9; ++j) {
            short8 bf = *reinterpret_cast<const short8*>(&Blds[(j * 16 + fm) * LDB + w * 32 + quad * 8]);
            acc[j] = __builtin_amdgcn_mfma_f32_16x16x32_bf16(af.s, bf, acc[j], 0, 0, 0);
        }
    }

    // epilogue: C/D layout col=lane&15, row=quad*4+reg; fp16 private partial per K-split
    unsigned short* out = Cp16 + (size_t)ks * (NAG * NB);
    #pragma unroll
    for (int j = 0; j < 9; ++j) {
        int col = j * 16 + fm;
        #pragma unroll
        for (int r = 0; r < 4; ++r) {
            int row = row0 + wave * 16 + quad * 4 + r;
            out[(size_t)row * NB + col] = f2h(acc[j][r]);
        }
    }
}

// ---------------- Kernel 3: reduce fp16 partials, msg=sum/deg, actor MLP ----------------
__global__ __launch_bounds__(256) void k3_actor(
    const float* __restrict__ h_f32,          // [8192][128]
    const unsigned short* __restrict__ Cp16,  // [NSPLIT][8192][144] fp16
    const void* __restrict__ W2,              // [256][128]
    const void* __restrict__ b2,              // [128]
    const void* __restrict__ W3,              // [128][16]
    const void* __restrict__ b3,              // [16]
    const int* __restrict__ flag,
    void* __restrict__ out)                   // [8192][16]
{
    __shared__ float4 comb4[16][66];   // [agent][c-quad], c = 0..255
    __shared__ float hid[16][132];
    __shared__ float inv_lds[16];
    const int t = threadIdx.x;
    const int abase = blockIdx.x * 16;
    const bool isf = (*flag != 0);
    const size_t PS = (size_t)NAG * NB;

    if (t < 16) {
        float deg = 0.f;
        #pragma unroll
        for (int s = 0; s < NSPLIT; ++s)
            deg += h2f(Cp16[s * PS + (size_t)(abase + t) * NB + 128]);
        inv_lds[t] = 1.0f / fmaxf(deg, 1.0f);
    }
    __syncthreads();

    #pragma unroll
    for (int jj = 0; jj < 4; ++jj) {
        int idx = jj * 256 + t;
        int a = idx >> 6, q = idx & 63;
        float4 v;
        if (q < 32) {   // h part
            v = *reinterpret_cast<const float4*>(h_f32 + (size_t)(abase + a) * 128 + q * 4);
        } else {        // msg part: sum NSPLIT fp16 partials, scale by 1/deg
            int f = (q - 32) * 4;
            float s0 = 0.f, s1 = 0.f, s2 = 0.f, s3 = 0.f;
            #pragma unroll
            for (int s = 0; s < NSPLIT; ++s) {
                ushort4 p = *reinterpret_cast<const ushort4*>(Cp16 + s * PS + (size_t)(abase + a) * NB + f);
                s0 += h2f(p.x); s1 += h2f(p.y); s2 += h2f(p.z); s3 += h2f(p.w);
            }
            float sc = inv_lds[a];
            v = make_float4(s0 * sc, s1 * sc, s2 * sc, s3 * sc);
        }
        comb4[a][q] = v;
    }
    __syncthreads();

    const int o = t & 127, half = t >> 7;   // 8 agents per half
    float acc[8];
    if (isf) {
        const float* Wp = (const float*)W2;
        float bias = ((const float*)b2)[o];
        #pragma unroll
        for (int i = 0; i < 8; ++i) acc[i] = bias;
        for (int cq = 0; cq < 64; ++cq) {
            float w0 = Wp[(cq * 4 + 0) * 128 + o];
            float w1 = Wp[(cq * 4 + 1) * 128 + o];
            float w2 = Wp[(cq * 4 + 2) * 128 + o];
            float w3 = Wp[(cq * 4 + 3) * 128 + o];
            #pragma unroll
            for (int i = 0; i < 8; ++i) {
                float4 v = comb4[half * 8 + i][cq];
                acc[i] = fmaf(v.x, w0, acc[i]);
                acc[i] = fmaf(v.y, w1, acc[i]);
                acc[i] = fmaf(v.z, w2, acc[i]);
                acc[i] = fmaf(v.w, w3, acc[i]);
            }
        }
    } else {
        const unsigned short* Wp = (const unsigned short*)W2;
        float bias = bf2f(((const unsigned short*)b2)[o]);
        #pragma unroll
        for (int i = 0; i < 8; ++i) acc[i] = bias;
        for (int cq = 0; cq < 64; ++cq) {
            float w0 = bf2f(Wp[(cq * 4 + 0) * 128 + o]);
            float w1 = bf2f(Wp[(cq * 4 + 1) * 128 + o]);
            float w2 = bf2f(Wp[(cq * 4 + 2) * 128 + o]);
            float w3 = bf2f(Wp[(cq * 4 + 3) * 128 + o]);
            #pragma unroll
            for (int i = 0; i < 8; ++i) {
                float4 v = comb4[half * 8 + i][cq];
                acc[i] = fmaf(v.x, w0, acc[i]);
                acc[i] = fmaf(v.y, w1, acc[i]);
                acc[i] = fmaf(v.z, w2, acc[i]);
                acc[i] = fmaf(v.w, w3, acc[i]);
            }
        }
    }
    #pragma unroll
    for (int i = 0; i < 8; ++i)
        hid[half * 8 + i][o] = tanhf(acc[i]);
    __syncthreads();

    const int q = t & 15, ar = t >> 4;
    float l;
    if (isf) {
        const float* Wp = (const float*)W3;
        l = ((const float*)b3)[q];
        #pragma unroll 4
        for (int oo = 0; oo < 128; ++oo)
            l = fmaf(hid[ar][oo], Wp[oo * 16 + q], l);
    } else {
        const unsigned short* Wp = (const unsigned short*)W3;
        l = bf2f(((const unsigned short*)b3)[q]);
        #pragma unroll 4
        for (int oo = 0; oo < 128; ++oo)
            l = fmaf(hid[ar][oo], bf2f(Wp[oo * 16 + q]), l);
    }
    size_t i0 = (size_t)(abase + ar) * 16 + q;
    if (isf) ((float*)out)[i0] = l;
    else     ((unsigned short*)out)[i0] = f2bf(l);
}

extern "C" void kernel_launch(void* const* d_in, const int* in_sizes, int n_in,
                              void* d_out, int out_size, void* d_ws, size_t ws_size,
                              hipStream_t stream) {
    const void* obs = d_in[0];
    const int*  adj = (const int*)d_in[1];
    const void* W1  = d_in[2];
    const void* b1  = d_in[3];
    const void* W2  = d_in[4];
    const void* b2  = d_in[5];
    const void* W3  = d_in[6];
    const void* b3  = d_in[7];

    char* ws = (char*)d_ws;
    unsigned short* hT   = (unsigned short*)(ws);               // 144*8192*2    =  2,359,296 B
    float*          h_f32= (float*)(ws + 2359296);              // 8192*128*4    =  4,194,304 B
    unsigned short* Cp16 = (unsigned short*)(ws + 6553600);     // 32*8192*144*2 = 75,497,472 B
    int*            flag = (int*)(ws + 82051072);               // 4 B  (total ~82 MB)

    hipLaunchKernelGGL(k0_init, dim3(1), dim3(64), 0, stream, flag, (const unsigned short*)W1);
    hipLaunchKernelGGL(k1_encode, dim3(256), dim3(256), 0, stream, obs, W1, b1, flag, h_f32, hT);
    hipLaunchKernelGGL(k2_msggemm, dim3(2048), dim3(512), 0, stream, adj, hT, Cp16);
    hipLaunchKernelGGL(k3_actor, dim3(512), dim3(256), 0, stream, h_f32, Cp16, W2, b2, W3, b3, flag, d_out);
}